// Round 1
// baseline (309.289 us; speedup 1.0000x reference)
//
#include <hip/hip_runtime.h>
#include <math.h>

#define BB 16
#define TT 1024
#define DD 512
#define T1 (TT + 1)
#define TAIL_C 0.45f

// ---------------------------------------------------------------------------
// Kernel 1: compute alphas2[b][t] for t in [0, T).
// One wave (64 lanes) per (b, t) row; each lane handles 8 channels.
// out[b,t,d] = relu( w0*h[t-1,d] + w1*h[t,d] + w2*h[t+1,d] + cb[d] + h[t,d] )
// logit[b,t] = sum_d out[b,t,d]*lin_w[d] + lin_b
// alphas2[b,t] = sigmoid(logit)*m[b,t] + (mask2 - m[b,t])*TAIL
// ---------------------------------------------------------------------------
__global__ __launch_bounds__(256) void alphas_kernel(
    const float* __restrict__ hidden, const float* __restrict__ mask,
    const float* __restrict__ conv_w, const float* __restrict__ conv_b,
    const float* __restrict__ lin_w, const float* __restrict__ lin_b,
    float* __restrict__ alphas2)
{
    const int wave = blockIdx.x * 4 + (threadIdx.x >> 6);
    const int lane = threadIdx.x & 63;
    const int b = wave / TT;
    const int t = wave % TT;
    const int d0 = lane * 8;

    const float* row0 = hidden + ((size_t)(b * TT + t)) * DD + d0;

    float4 h0a = *(const float4*)(row0);
    float4 h0b = *(const float4*)(row0 + 4);
    float4 hma, hmb, hpa, hpb;
    if (t > 0) {
        hma = *(const float4*)(row0 - DD);
        hmb = *(const float4*)(row0 - DD + 4);
    } else {
        hma = make_float4(0.f, 0.f, 0.f, 0.f);
        hmb = make_float4(0.f, 0.f, 0.f, 0.f);
    }
    if (t < TT - 1) {
        hpa = *(const float4*)(row0 + DD);
        hpb = *(const float4*)(row0 + DD + 4);
    } else {
        hpa = make_float4(0.f, 0.f, 0.f, 0.f);
        hpb = make_float4(0.f, 0.f, 0.f, 0.f);
    }

    float hm[8] = {hma.x, hma.y, hma.z, hma.w, hmb.x, hmb.y, hmb.z, hmb.w};
    float h0[8] = {h0a.x, h0a.y, h0a.z, h0a.w, h0b.x, h0b.y, h0b.z, h0b.w};
    float hp[8] = {hpa.x, hpa.y, hpa.z, hpa.w, hpb.x, hpb.y, hpb.z, hpb.w};

    const float* cw = conv_w + (size_t)d0 * 3;
    const float* cb = conv_b + d0;
    const float* lw = lin_w + d0;

    float acc = 0.f;
#pragma unroll
    for (int j = 0; j < 8; ++j) {
        float x = cw[j * 3 + 0] * hm[j] + cw[j * 3 + 1] * h0[j] +
                  cw[j * 3 + 2] * hp[j] + cb[j] + h0[j];
        x = fmaxf(x, 0.f);
        acc += x * lw[j];
    }
#pragma unroll
    for (int off = 32; off > 0; off >>= 1) acc += __shfl_xor(acc, off, 64);

    if (lane == 0) {
        float logit = acc + lin_b[0];
        float alpha = 1.f / (1.f + expf(-logit));
        float m = mask[b * TT + t];
        // SMOOTH = 1, NOISE = 0 (keep general form)
        float a = fmaxf(alpha * 1.0f - 0.0f, 0.f) * m;
        float m2 = (t == 0) ? 1.0f : mask[b * TT + t - 1];
        alphas2[(size_t)b * T1 + t] = a + (m2 - m) * TAIL_C;
    }
}

// ---------------------------------------------------------------------------
// Kernel 2: CIF scan. One block per batch, 512 threads (one per channel).
// Scalar integrate/fire recurrence computed redundantly by all threads
// (identical values, no communication). frame state in one register/thread.
// ---------------------------------------------------------------------------
__global__ __launch_bounds__(512) void cif_scan_kernel(
    const float* __restrict__ hidden, const float* __restrict__ mask,
    float* __restrict__ acoustic, float* __restrict__ token_num,
    float* __restrict__ alphas2, float* __restrict__ cif_peak)
{
    __shared__ float s_alpha[T1];
    __shared__ float s_red[8];

    const int b = blockIdx.x;
    const int tid = threadIdx.x;

    // finalize alphas2[b][T] = mask[b][T-1] * TAIL  (tail term; alphas part is 0)
    if (tid == 0) {
        float aT = mask[b * TT + TT - 1] * TAIL_C;
        alphas2[(size_t)b * T1 + TT] = aT;
        s_alpha[TT] = aT;
    }

    float part = 0.f;
    for (int i = tid; i < TT; i += 512) {
        float a = alphas2[(size_t)b * T1 + i];
        s_alpha[i] = a;
        part += a;
    }
#pragma unroll
    for (int off = 32; off > 0; off >>= 1) part += __shfl_xor(part, off, 64);
    if ((tid & 63) == 0) s_red[tid >> 6] = part;
    __syncthreads();

    if (tid == 0) {
        float s = s_alpha[TT];
#pragma unroll
        for (int w = 0; w < 8; ++w) s += s_red[w];
        token_num[b] = floorf(s);
    }

    // main sequential scan over t = 0..T (inclusive; hidden row T is zeros)
    const float* hrow = hidden + (size_t)b * TT * DD + tid;
    float* aco = acoustic + (size_t)b * T1 * DD + tid;
    float* peak = cif_peak + (size_t)b * T1;

    float integrate = 0.f;
    float frame = 0.f;
    int fcount = 0;

    float h_next = hrow[0];  // t = 0 row
    for (int t = 0; t <= TT; ++t) {
        float h = h_next;
        h_next = (t + 1 < TT) ? hrow[(size_t)(t + 1) * DD] : 0.f;

        float alpha = s_alpha[t];
        float dist = 1.f - integrate;
        integrate += alpha;
        if (tid == 0) peak[t] = integrate;  // fires_t (pre-subtraction)
        bool fire = (integrate >= 1.0f);
        float cur = fire ? dist : alpha;
        frame += cur * h;
        if (fire) {
            aco[(size_t)fcount * DD] = frame;      // frames_t scattered to pos
            frame = (alpha - cur) * h;             // rem * h_t
            fcount++;
            integrate -= 1.0f;
        }
    }
}

extern "C" void kernel_launch(void* const* d_in, const int* in_sizes, int n_in,
                              void* d_out, int out_size, void* d_ws, size_t ws_size,
                              hipStream_t stream) {
    const float* hidden = (const float*)d_in[0];
    const float* mask   = (const float*)d_in[1];
    const float* conv_w = (const float*)d_in[2];
    const float* conv_b = (const float*)d_in[3];
    const float* lin_w  = (const float*)d_in[4];
    const float* lin_b  = (const float*)d_in[5];

    float* out       = (float*)d_out;
    float* out_aco   = out;                                   // B*T1*D
    float* out_tok   = out + (size_t)BB * T1 * DD;            // B
    float* out_alp   = out_tok + BB;                          // B*T1
    float* out_peak  = out_alp + (size_t)BB * T1;             // B*T1

    // acoustic rows that never fire must be zero
    hipMemsetAsync(out_aco, 0, (size_t)BB * T1 * DD * sizeof(float), stream);

    alphas_kernel<<<(BB * TT) / 4, 256, 0, stream>>>(
        hidden, mask, conv_w, conv_b, lin_w, lin_b, out_alp);

    cif_scan_kernel<<<BB, 512, 0, stream>>>(
        hidden, mask, out_aco, out_tok, out_alp, out_peak);
}

// Round 2
// 174.317 us; speedup vs baseline: 1.7743x; 1.7743x over previous
//
#include <hip/hip_runtime.h>
#include <math.h>

#define BB 16
#define TT 1024
#define DD 512
#define T1 (TT + 1)
#define TAIL_C 0.45f
#define CH 8   // t-rows per wave in alphas kernel

// ---------------------------------------------------------------------------
// Kernel 1: alphas2[b][t], t in [0,TT), plus tail element at t=TT.
// One wave per (b, 8 consecutive t). Register-rolled 3-row window.
// ---------------------------------------------------------------------------
__global__ __launch_bounds__(256) void alphas_kernel(
    const float* __restrict__ hidden, const float* __restrict__ mask,
    const float* __restrict__ conv_w, const float* __restrict__ conv_b,
    const float* __restrict__ lin_w, const float* __restrict__ lin_b,
    float* __restrict__ alphas2)
{
    const int wave = blockIdx.x * 4 + (threadIdx.x >> 6);
    const int lane = threadIdx.x & 63;
    const int b = wave / (TT / CH);
    const int c = wave % (TT / CH);
    const int t0 = c * CH;
    const int d0 = lane * 8;

    // per-lane weights for channels d0..d0+7
    float cw[24], cb[8], lw[8];
    {
        const float4* p = (const float4*)(conv_w + (size_t)d0 * 3);
#pragma unroll
        for (int j = 0; j < 6; ++j) {
            float4 v = p[j];
            cw[j * 4 + 0] = v.x; cw[j * 4 + 1] = v.y;
            cw[j * 4 + 2] = v.z; cw[j * 4 + 3] = v.w;
        }
        float4 b0 = *(const float4*)(conv_b + d0);
        float4 b1 = *(const float4*)(conv_b + d0 + 4);
        cb[0]=b0.x; cb[1]=b0.y; cb[2]=b0.z; cb[3]=b0.w;
        cb[4]=b1.x; cb[5]=b1.y; cb[6]=b1.z; cb[7]=b1.w;
        float4 l0 = *(const float4*)(lin_w + d0);
        float4 l1 = *(const float4*)(lin_w + d0 + 4);
        lw[0]=l0.x; lw[1]=l0.y; lw[2]=l0.z; lw[3]=l0.w;
        lw[4]=l1.x; lw[5]=l1.y; lw[6]=l1.z; lw[7]=l1.w;
    }

    const float* base = hidden + (size_t)b * TT * DD + d0;
    float hm[8], h0[8], hp[8], acc[CH];

    if (t0 > 0) {
        float4 a = *(const float4*)(base + (size_t)(t0 - 1) * DD);
        float4 bq = *(const float4*)(base + (size_t)(t0 - 1) * DD + 4);
        hm[0]=a.x; hm[1]=a.y; hm[2]=a.z; hm[3]=a.w;
        hm[4]=bq.x; hm[5]=bq.y; hm[6]=bq.z; hm[7]=bq.w;
    } else {
#pragma unroll
        for (int j = 0; j < 8; ++j) hm[j] = 0.f;
    }
    {
        float4 a = *(const float4*)(base + (size_t)t0 * DD);
        float4 bq = *(const float4*)(base + (size_t)t0 * DD + 4);
        h0[0]=a.x; h0[1]=a.y; h0[2]=a.z; h0[3]=a.w;
        h0[4]=bq.x; h0[5]=bq.y; h0[6]=bq.z; h0[7]=bq.w;
    }

#pragma unroll
    for (int r = 0; r < CH; ++r) {
        const int t = t0 + r;
        if (t + 1 < TT) {
            float4 a = *(const float4*)(base + (size_t)(t + 1) * DD);
            float4 bq = *(const float4*)(base + (size_t)(t + 1) * DD + 4);
            hp[0]=a.x; hp[1]=a.y; hp[2]=a.z; hp[3]=a.w;
            hp[4]=bq.x; hp[5]=bq.y; hp[6]=bq.z; hp[7]=bq.w;
        } else {
#pragma unroll
            for (int j = 0; j < 8; ++j) hp[j] = 0.f;
        }
        float s = 0.f;
#pragma unroll
        for (int j = 0; j < 8; ++j) {
            float x = fmaf(cw[3*j], hm[j],
                      fmaf(cw[3*j+1], h0[j],
                      fmaf(cw[3*j+2], hp[j], cb[j]))) + h0[j];
            x = fmaxf(x, 0.f);
            s = fmaf(x, lw[j], s);
        }
        acc[r] = s;
#pragma unroll
        for (int j = 0; j < 8; ++j) { hm[j] = h0[j]; h0[j] = hp[j]; }
    }

    // 8 independent wave reductions (pipelined chains)
#pragma unroll
    for (int r = 0; r < CH; ++r) {
#pragma unroll
        for (int off = 32; off; off >>= 1) acc[r] += __shfl_xor(acc[r], off, 64);
    }

    if (lane < CH) {
        float v = acc[0];
#pragma unroll
        for (int r = 1; r < CH; ++r) v = (lane == r) ? acc[r] : v;
        const int t = t0 + lane;
        float logit = v + lin_b[0];
        float alpha = 1.f / (1.f + expf(-logit));
        float m = mask[b * TT + t];
        float a = fmaxf(alpha, 0.f) * m;              // SMOOTH=1, NOISE=0
        float m2 = (t == 0) ? 1.0f : mask[b * TT + t - 1];
        alphas2[(size_t)b * T1 + t] = a + (m2 - m) * TAIL_C;
    } else if (lane == CH && c == 0) {
        // tail element t = TT
        alphas2[(size_t)b * T1 + TT] = mask[b * TT + TT - 1] * TAIL_C;
    }
}

// ---------------------------------------------------------------------------
// Phase A: exact sequential integrate recurrence, one lane per batch.
// Writes cif_peak, token_num, fire positions + counts (to workspace).
// ---------------------------------------------------------------------------
__global__ __launch_bounds__(256) void cif_phase_a(
    const float* __restrict__ alphas2, float* __restrict__ token_num,
    float* __restrict__ cif_peak, int* __restrict__ fire_pos,
    int* __restrict__ n_fires)
{
    __shared__ float s_a[BB * T1];   // 65.6 KB
    const int tid = threadIdx.x;
    for (int i = tid; i < BB * T1; i += 256) s_a[i] = alphas2[i];
    __syncthreads();

    // token_num = floor(sum of alphas2 per batch); threshold is loose
    {
        const int b = tid >> 4, i = tid & 15;
        float part = 0.f;
        for (int t = i; t < T1; t += 16) part += s_a[b * T1 + t];
        part += __shfl_xor(part, 1, 64);
        part += __shfl_xor(part, 2, 64);
        part += __shfl_xor(part, 4, 64);
        part += __shfl_xor(part, 8, 64);
        if (i == 0) token_num[b] = floorf(part);
    }

    if (tid < BB) {
        const int b = tid;
        const float* sa = s_a + b * T1;
        float* peak = cif_peak + b * T1;
        int* fp = fire_pos + b * T1;
        float integ = 0.f;
        int k = 0;
        for (int t = 0; t < T1; ++t) {
            float a = sa[t];
            integ += a;              // exact reference op order
            peak[t] = integ;         // fires_t (pre-subtraction)
            bool fire = (integ >= 1.0f);
            if (fire) {
                fp[k] = t;
                ++k;
                integ -= 1.0f;
            }
        }
        n_fires[b] = k;
    }
}

// ---------------------------------------------------------------------------
// Phase B: one wave per acoustic output row. Fired rows = segment-weighted
// sum of hidden rows; boundary weights reconstructed from peak/alphas:
//   rem_t  = peak_t - 1
//   dist_t = 1 - peak_t + alpha_t
// Non-fired rows write zeros (replaces memset).
// ---------------------------------------------------------------------------
__global__ __launch_bounds__(256) void cif_gather(
    const float* __restrict__ hidden, const float* __restrict__ alphas2,
    const float* __restrict__ cif_peak, const int* __restrict__ fire_pos,
    const int* __restrict__ n_fires, float* __restrict__ acoustic)
{
    const int wave = blockIdx.x * 4 + (threadIdx.x >> 6);
    const int lane = threadIdx.x & 63;
    const int b = wave / T1;
    const int k = wave % T1;
    const int d0 = lane * 8;

    float4 acc0 = make_float4(0.f, 0.f, 0.f, 0.f);
    float4 acc1 = make_float4(0.f, 0.f, 0.f, 0.f);

    const int nf = n_fires[b];
    if (k < nf) {
        const int te = fire_pos[b * T1 + k];
        int ts; float wstart;
        if (k == 0) {
            ts = 0;
            wstart = alphas2[b * T1];           // alpha_0
        } else {
            ts = fire_pos[b * T1 + k - 1];
            wstart = cif_peak[b * T1 + ts] - 1.0f;   // rem at prev fire
        }
        const float ae = alphas2[b * T1 + te];
        const float wend = 1.0f - cif_peak[b * T1 + te] + ae;  // dist at te

        for (int t = ts; t <= te; ++t) {
            if (t >= TT) break;   // hidden2 row TT is zeros
            float w = (t == te) ? wend : (t == ts) ? wstart
                                       : alphas2[b * T1 + t];
            const float* hrow = hidden + (size_t)(b * TT + t) * DD + d0;
            float4 h0 = *(const float4*)hrow;
            float4 h1 = *(const float4*)(hrow + 4);
            acc0.x = fmaf(w, h0.x, acc0.x);
            acc0.y = fmaf(w, h0.y, acc0.y);
            acc0.z = fmaf(w, h0.z, acc0.z);
            acc0.w = fmaf(w, h0.w, acc0.w);
            acc1.x = fmaf(w, h1.x, acc1.x);
            acc1.y = fmaf(w, h1.y, acc1.y);
            acc1.z = fmaf(w, h1.z, acc1.z);
            acc1.w = fmaf(w, h1.w, acc1.w);
        }
    }
    float* arow = acoustic + (size_t)(b * T1 + k) * DD + d0;
    *(float4*)arow = acc0;
    *(float4*)(arow + 4) = acc1;
}

extern "C" void kernel_launch(void* const* d_in, const int* in_sizes, int n_in,
                              void* d_out, int out_size, void* d_ws, size_t ws_size,
                              hipStream_t stream) {
    const float* hidden = (const float*)d_in[0];
    const float* mask   = (const float*)d_in[1];
    const float* conv_w = (const float*)d_in[2];
    const float* conv_b = (const float*)d_in[3];
    const float* lin_w  = (const float*)d_in[4];
    const float* lin_b  = (const float*)d_in[5];

    float* out       = (float*)d_out;
    float* out_aco   = out;                                   // B*T1*D
    float* out_tok   = out + (size_t)BB * T1 * DD;            // B
    float* out_alp   = out_tok + BB;                          // B*T1
    float* out_peak  = out_alp + (size_t)BB * T1;             // B*T1

    int* fire_pos = (int*)d_ws;                               // B*T1 ints
    int* nf       = fire_pos + (size_t)BB * T1;               // B ints

    alphas_kernel<<<(BB * (TT / CH)) / 4, 256, 0, stream>>>(
        hidden, mask, conv_w, conv_b, lin_w, lin_b, out_alp);

    cif_phase_a<<<1, 256, 0, stream>>>(
        out_alp, out_tok, out_peak, fire_pos, nf);

    cif_gather<<<(BB * T1) / 4, 256, 0, stream>>>(
        hidden, out_alp, out_peak, fire_pos, nf, out_aco);
}

// Round 3
// 164.979 us; speedup vs baseline: 1.8747x; 1.0566x over previous
//
#include <hip/hip_runtime.h>
#include <math.h>

#define BB 16
#define TT 1024
#define DD 512
#define T1 (TT + 1)
#define TAIL_C 0.45f
#define CH 8   // t-rows per wave in alphas kernel

// ---------------------------------------------------------------------------
// Kernel 1: alphas2[b][t], t in [0,TT), plus tail element at t=TT.
// One wave per (b, 8 consecutive t). Register-rolled 3-row window.
// ---------------------------------------------------------------------------
__global__ __launch_bounds__(256) void alphas_kernel(
    const float* __restrict__ hidden, const float* __restrict__ mask,
    const float* __restrict__ conv_w, const float* __restrict__ conv_b,
    const float* __restrict__ lin_w, const float* __restrict__ lin_b,
    float* __restrict__ alphas2)
{
    const int wave = blockIdx.x * 4 + (threadIdx.x >> 6);
    const int lane = threadIdx.x & 63;
    const int b = wave / (TT / CH);
    const int c = wave % (TT / CH);
    const int t0 = c * CH;
    const int d0 = lane * 8;

    // per-lane weights for channels d0..d0+7
    float cw[24], cb[8], lw[8];
    {
        const float4* p = (const float4*)(conv_w + (size_t)d0 * 3);
#pragma unroll
        for (int j = 0; j < 6; ++j) {
            float4 v = p[j];
            cw[j * 4 + 0] = v.x; cw[j * 4 + 1] = v.y;
            cw[j * 4 + 2] = v.z; cw[j * 4 + 3] = v.w;
        }
        float4 b0 = *(const float4*)(conv_b + d0);
        float4 b1 = *(const float4*)(conv_b + d0 + 4);
        cb[0]=b0.x; cb[1]=b0.y; cb[2]=b0.z; cb[3]=b0.w;
        cb[4]=b1.x; cb[5]=b1.y; cb[6]=b1.z; cb[7]=b1.w;
        float4 l0 = *(const float4*)(lin_w + d0);
        float4 l1 = *(const float4*)(lin_w + d0 + 4);
        lw[0]=l0.x; lw[1]=l0.y; lw[2]=l0.z; lw[3]=l0.w;
        lw[4]=l1.x; lw[5]=l1.y; lw[6]=l1.z; lw[7]=l1.w;
    }

    const float* base = hidden + (size_t)b * TT * DD + d0;
    float hm[8], h0[8], hp[8], acc[CH];

    if (t0 > 0) {
        float4 a = *(const float4*)(base + (size_t)(t0 - 1) * DD);
        float4 bq = *(const float4*)(base + (size_t)(t0 - 1) * DD + 4);
        hm[0]=a.x; hm[1]=a.y; hm[2]=a.z; hm[3]=a.w;
        hm[4]=bq.x; hm[5]=bq.y; hm[6]=bq.z; hm[7]=bq.w;
    } else {
#pragma unroll
        for (int j = 0; j < 8; ++j) hm[j] = 0.f;
    }
    {
        float4 a = *(const float4*)(base + (size_t)t0 * DD);
        float4 bq = *(const float4*)(base + (size_t)t0 * DD + 4);
        h0[0]=a.x; h0[1]=a.y; h0[2]=a.z; h0[3]=a.w;
        h0[4]=bq.x; h0[5]=bq.y; h0[6]=bq.z; h0[7]=bq.w;
    }

#pragma unroll
    for (int r = 0; r < CH; ++r) {
        const int t = t0 + r;
        if (t + 1 < TT) {
            float4 a = *(const float4*)(base + (size_t)(t + 1) * DD);
            float4 bq = *(const float4*)(base + (size_t)(t + 1) * DD + 4);
            hp[0]=a.x; hp[1]=a.y; hp[2]=a.z; hp[3]=a.w;
            hp[4]=bq.x; hp[5]=bq.y; hp[6]=bq.z; hp[7]=bq.w;
        } else {
#pragma unroll
            for (int j = 0; j < 8; ++j) hp[j] = 0.f;
        }
        float s = 0.f;
#pragma unroll
        for (int j = 0; j < 8; ++j) {
            float x = fmaf(cw[3*j], hm[j],
                      fmaf(cw[3*j+1], h0[j],
                      fmaf(cw[3*j+2], hp[j], cb[j]))) + h0[j];
            x = fmaxf(x, 0.f);
            s = fmaf(x, lw[j], s);
        }
        acc[r] = s;
#pragma unroll
        for (int j = 0; j < 8; ++j) { hm[j] = h0[j]; h0[j] = hp[j]; }
    }

    // 8 independent wave reductions (pipelined chains)
#pragma unroll
    for (int r = 0; r < CH; ++r) {
#pragma unroll
        for (int off = 32; off; off >>= 1) acc[r] += __shfl_xor(acc[r], off, 64);
    }

    if (lane < CH) {
        float v = acc[0];
#pragma unroll
        for (int r = 1; r < CH; ++r) v = (lane == r) ? acc[r] : v;
        const int t = t0 + lane;
        float logit = v + lin_b[0];
        float alpha = 1.f / (1.f + expf(-logit));
        float m = mask[b * TT + t];
        float a = fmaxf(alpha, 0.f) * m;              // SMOOTH=1, NOISE=0
        float m2 = (t == 0) ? 1.0f : mask[b * TT + t - 1];
        alphas2[(size_t)b * T1 + t] = a + (m2 - m) * TAIL_C;
    } else if (lane == CH && c == 0) {
        // tail element t = TT
        alphas2[(size_t)b * T1 + TT] = mask[b * TT + TT - 1] * TAIL_C;
    }
}

// ---------------------------------------------------------------------------
// Phase A: exact sequential integrate recurrence, one lane per batch.
// Register double-buffered alpha prefetch (16-step chunks); critical chain is
// add + v_fract per step (fract(s) == reference's conditional subtract, exact
// on s in [0,2)). Fire positions via predicated stores off the chain.
// ---------------------------------------------------------------------------
__global__ __launch_bounds__(256) void cif_phase_a(
    const float* __restrict__ alphas2, float* __restrict__ token_num,
    float* __restrict__ cif_peak, int* __restrict__ fire_pos,
    int* __restrict__ n_fires)
{
    const int tid = threadIdx.x;

    // token_num = floor(sum alphas2 per batch) — identical order to r2 (passed)
    {
        const int b = tid >> 4, i = tid & 15;
        float part = 0.f;
        for (int t = i; t < T1; t += 16) part += alphas2[b * T1 + t];
        part += __shfl_xor(part, 1, 64);
        part += __shfl_xor(part, 2, 64);
        part += __shfl_xor(part, 4, 64);
        part += __shfl_xor(part, 8, 64);
        if (i == 0) token_num[b] = floorf(part);
    }

    if (tid < BB) {
        const int b = tid;
        const float* sa = alphas2 + b * T1;
        float* peak = cif_peak + b * T1;
        int* fp = fire_pos + b * T1;

        float cur[16], nxt[16];
#pragma unroll
        for (int j = 0; j < 16; ++j) cur[j] = sa[j];

        float integ = 0.f;
        int k = 0;
        for (int c = 0; c < 64; ++c) {
            if (c < 63) {
#pragma unroll
                for (int j = 0; j < 16; ++j) nxt[j] = sa[(c + 1) * 16 + j];
            }
#pragma unroll
            for (int j = 0; j < 16; ++j) {
                float s = integ + cur[j];
                peak[c * 16 + j] = s;
                if (s >= 1.0f) { fp[k] = c * 16 + j; ++k; }
                asm("v_fract_f32 %0, %1" : "=v"(integ) : "v"(s));
            }
#pragma unroll
            for (int j = 0; j < 16; ++j) cur[j] = nxt[j];
        }
        // tail t = 1024
        float s = integ + sa[TT];
        peak[TT] = s;
        if (s >= 1.0f) { fp[k] = TT; ++k; }
        n_fires[b] = k;
    }
}

// ---------------------------------------------------------------------------
// Phase B: one wave per acoustic output row. Fired rows = segment-weighted
// sum of hidden rows; boundary weights reconstructed from peak/alphas:
//   rem_t  = peak_t - 1
//   dist_t = 1 - peak_t + alpha_t
// Non-fired rows write zeros (replaces memset).
// ---------------------------------------------------------------------------
__global__ __launch_bounds__(256) void cif_gather(
    const float* __restrict__ hidden, const float* __restrict__ alphas2,
    const float* __restrict__ cif_peak, const int* __restrict__ fire_pos,
    const int* __restrict__ n_fires, float* __restrict__ acoustic)
{
    const int wave = blockIdx.x * 4 + (threadIdx.x >> 6);
    const int lane = threadIdx.x & 63;
    const int b = wave / T1;
    const int k = wave % T1;
    const int d0 = lane * 8;

    float4 acc0 = make_float4(0.f, 0.f, 0.f, 0.f);
    float4 acc1 = make_float4(0.f, 0.f, 0.f, 0.f);

    const int nf = n_fires[b];
    if (k < nf) {
        const int te = fire_pos[b * T1 + k];
        int ts; float wstart;
        if (k == 0) {
            ts = 0;
            wstart = alphas2[b * T1];                // alpha_0
        } else {
            ts = fire_pos[b * T1 + k - 1];
            wstart = cif_peak[b * T1 + ts] - 1.0f;   // rem at prev fire
        }
        const float ae = alphas2[b * T1 + te];
        const float wend = 1.0f - cif_peak[b * T1 + te] + ae;  // dist at te

        for (int t = ts; t <= te; ++t) {
            if (t >= TT) break;   // hidden2 row TT is zeros
            float w = (t == te) ? wend : (t == ts) ? wstart
                                       : alphas2[b * T1 + t];
            const float* hrow = hidden + (size_t)(b * TT + t) * DD + d0;
            float4 h0 = *(const float4*)hrow;
            float4 h1 = *(const float4*)(hrow + 4);
            acc0.x = fmaf(w, h0.x, acc0.x);
            acc0.y = fmaf(w, h0.y, acc0.y);
            acc0.z = fmaf(w, h0.z, acc0.z);
            acc0.w = fmaf(w, h0.w, acc0.w);
            acc1.x = fmaf(w, h1.x, acc1.x);
            acc1.y = fmaf(w, h1.y, acc1.y);
            acc1.z = fmaf(w, h1.z, acc1.z);
            acc1.w = fmaf(w, h1.w, acc1.w);
        }
    }
    float* arow = acoustic + (size_t)(b * T1 + k) * DD + d0;
    *(float4*)arow = acc0;
    *(float4*)(arow + 4) = acc1;
}

extern "C" void kernel_launch(void* const* d_in, const int* in_sizes, int n_in,
                              void* d_out, int out_size, void* d_ws, size_t ws_size,
                              hipStream_t stream) {
    const float* hidden = (const float*)d_in[0];
    const float* mask   = (const float*)d_in[1];
    const float* conv_w = (const float*)d_in[2];
    const float* conv_b = (const float*)d_in[3];
    const float* lin_w  = (const float*)d_in[4];
    const float* lin_b  = (const float*)d_in[5];

    float* out       = (float*)d_out;
    float* out_aco   = out;                                   // B*T1*D
    float* out_tok   = out + (size_t)BB * T1 * DD;            // B
    float* out_alp   = out_tok + BB;                          // B*T1
    float* out_peak  = out_alp + (size_t)BB * T1;             // B*T1

    int* fire_pos = (int*)d_ws;                               // B*T1 ints
    int* nf       = fire_pos + (size_t)BB * T1;               // B ints

    alphas_kernel<<<(BB * (TT / CH)) / 4, 256, 0, stream>>>(
        hidden, mask, conv_w, conv_b, lin_w, lin_b, out_alp);

    cif_phase_a<<<1, 256, 0, stream>>>(
        out_alp, out_tok, out_peak, fire_pos, nf);

    cif_gather<<<(BB * T1) / 4, 256, 0, stream>>>(
        hidden, out_alp, out_peak, fire_pos, nf, out_aco);
}

// Round 4
// 154.788 us; speedup vs baseline: 1.9981x; 1.0658x over previous
//
#include <hip/hip_runtime.h>
#include <math.h>

#define BB 16
#define TT 1024
#define DD 512
#define T1 (TT + 1)
#define TAIL_C 0.45f
#define CH 8   // t-rows per wave in alphas kernel

// ---------------------------------------------------------------------------
// Kernel 1: alphas2[b][t], t in [0,TT), plus tail element at t=TT.
// One wave per (b, 8 consecutive t). All 10 hidden rows loaded UP FRONT so
// the 20 dwordx4 loads are in flight together (one latency exposure/wave).
// ---------------------------------------------------------------------------
__global__ __launch_bounds__(256) void alphas_kernel(
    const float* __restrict__ hidden, const float* __restrict__ mask,
    const float* __restrict__ conv_w, const float* __restrict__ conv_b,
    const float* __restrict__ lin_w, const float* __restrict__ lin_b,
    float* __restrict__ alphas2)
{
    const int wave = blockIdx.x * 4 + (threadIdx.x >> 6);
    const int lane = threadIdx.x & 63;
    const int b = wave / (TT / CH);
    const int c = wave % (TT / CH);
    const int t0 = c * CH;
    const int d0 = lane * 8;

    // per-lane weights for channels d0..d0+7
    float cw[24], cb[8], lw[8];
    {
        const float4* p = (const float4*)(conv_w + (size_t)d0 * 3);
#pragma unroll
        for (int j = 0; j < 6; ++j) {
            float4 v = p[j];
            cw[j * 4 + 0] = v.x; cw[j * 4 + 1] = v.y;
            cw[j * 4 + 2] = v.z; cw[j * 4 + 3] = v.w;
        }
        float4 b0 = *(const float4*)(conv_b + d0);
        float4 b1 = *(const float4*)(conv_b + d0 + 4);
        cb[0]=b0.x; cb[1]=b0.y; cb[2]=b0.z; cb[3]=b0.w;
        cb[4]=b1.x; cb[5]=b1.y; cb[6]=b1.z; cb[7]=b1.w;
        float4 l0 = *(const float4*)(lin_w + d0);
        float4 l1 = *(const float4*)(lin_w + d0 + 4);
        lw[0]=l0.x; lw[1]=l0.y; lw[2]=l0.z; lw[3]=l0.w;
        lw[4]=l1.x; lw[5]=l1.y; lw[6]=l1.z; lw[7]=l1.w;
    }

    const float* base = hidden + (size_t)b * TT * DD + d0;

    // rows[r] = hidden row (t0 - 1 + r), r = 0..9; zeros outside [0, TT)
    float rows[CH + 2][8];
#pragma unroll
    for (int r = 0; r < CH + 2; ++r) {
        const int t = t0 - 1 + r;
        if (t >= 0 && t < TT) {
            float4 a  = *(const float4*)(base + (size_t)t * DD);
            float4 bq = *(const float4*)(base + (size_t)t * DD + 4);
            rows[r][0]=a.x;  rows[r][1]=a.y;  rows[r][2]=a.z;  rows[r][3]=a.w;
            rows[r][4]=bq.x; rows[r][5]=bq.y; rows[r][6]=bq.z; rows[r][7]=bq.w;
        } else {
#pragma unroll
            for (int j = 0; j < 8; ++j) rows[r][j] = 0.f;
        }
    }

    float acc[CH];
#pragma unroll
    for (int r = 0; r < CH; ++r) {
        float s = 0.f;
#pragma unroll
        for (int j = 0; j < 8; ++j) {
            float x = fmaf(cw[3*j],   rows[r][j],
                      fmaf(cw[3*j+1], rows[r+1][j],
                      fmaf(cw[3*j+2], rows[r+2][j], cb[j]))) + rows[r+1][j];
            x = fmaxf(x, 0.f);
            s = fmaf(x, lw[j], s);
        }
        acc[r] = s;
    }

    // 8 independent wave reductions (pipelined chains)
#pragma unroll
    for (int r = 0; r < CH; ++r) {
#pragma unroll
        for (int off = 32; off; off >>= 1) acc[r] += __shfl_xor(acc[r], off, 64);
    }

    if (lane < CH) {
        float v = acc[0];
#pragma unroll
        for (int r = 1; r < CH; ++r) v = (lane == r) ? acc[r] : v;
        const int t = t0 + lane;
        float logit = v + lin_b[0];
        float alpha = 1.f / (1.f + expf(-logit));
        float m = mask[b * TT + t];
        float a = fmaxf(alpha, 0.f) * m;              // SMOOTH=1, NOISE=0
        float m2 = (t == 0) ? 1.0f : mask[b * TT + t - 1];
        alphas2[(size_t)b * T1 + t] = a + (m2 - m) * TAIL_C;
    } else if (lane == CH && c == 0) {
        // tail element t = TT
        alphas2[(size_t)b * T1 + TT] = mask[b * TT + TT - 1] * TAIL_C;
    }
}

// ---------------------------------------------------------------------------
// Phase A: exact sequential integrate recurrence, one lane per batch.
// Alphas staged in LDS (lgkmcnt domain — decoupled from peak/fp stores which
// live in vmcnt). Chain = add + v_fract only (fract(s) == reference's
// conditional subtract, exact on s in [0,2)). Peaks overwrite alphas in-place
// in LDS; cooperative float4 writeback at the end.
// ---------------------------------------------------------------------------
__global__ __launch_bounds__(256) void cif_phase_a(
    const float* __restrict__ alphas2, float* __restrict__ token_num,
    float* __restrict__ cif_peak, int* __restrict__ fire_pos,
    int* __restrict__ n_fires)
{
    __shared__ float s_a[BB * T1];   // 65.6 KB flat mirror (alphas -> peaks)
    const int tid = threadIdx.x;

    // stage alphas: 16400 floats = 4100 float4, both sides 16B aligned
    {
        const float4* src = (const float4*)alphas2;
        float4* dst = (float4*)s_a;
        for (int i = tid; i < (BB * T1) / 4; i += 256) dst[i] = src[i];
    }
    __syncthreads();

    // token_num = floor(sum alphas2 per batch) — identical order to r2/r3
    {
        const int b = tid >> 4, i = tid & 15;
        float part = 0.f;
        for (int t = i; t < T1; t += 16) part += s_a[b * T1 + t];
        part += __shfl_xor(part, 1, 64);
        part += __shfl_xor(part, 2, 64);
        part += __shfl_xor(part, 4, 64);
        part += __shfl_xor(part, 8, 64);
        if (i == 0) token_num[b] = floorf(part);
    }
    __syncthreads();   // chain below overwrites s_a rows other waves just read

    if (tid < BB) {
        float* sa = s_a + tid * T1;      // stride 1025 (odd) -> conflict-free
        int* fp = fire_pos + tid * T1;
        float integ = 0.f;
        int k = 0;
        for (int c = 0; c < 64; ++c) {
            float cur[16], pk[16];
#pragma unroll
            for (int j = 0; j < 16; ++j) cur[j] = sa[c * 16 + j];
#pragma unroll
            for (int j = 0; j < 16; ++j) {          // the serial chain
                float s = integ + cur[j];
                pk[j] = s;
                asm("v_fract_f32 %0, %1" : "=v"(integ) : "v"(s));
            }
#pragma unroll
            for (int j = 0; j < 16; ++j) {          // off-chain bookkeeping
                sa[c * 16 + j] = pk[j];
                if (pk[j] >= 1.0f) { fp[k] = c * 16 + j; ++k; }
            }
        }
        // tail t = 1024
        float s = integ + sa[TT];
        sa[TT] = s;
        if (s >= 1.0f) { fp[k] = TT; ++k; }
        n_fires[tid] = k;
    }
    __syncthreads();

    // writeback peaks
    {
        const float4* src = (const float4*)s_a;
        float4* dst = (float4*)cif_peak;
        for (int i = tid; i < (BB * T1) / 4; i += 256) dst[i] = src[i];
    }
}

// ---------------------------------------------------------------------------
// Phase B: one wave per acoustic output row. Fired rows = segment-weighted
// sum of hidden rows; boundary weights reconstructed from peak/alphas:
//   rem_t  = peak_t - 1
//   dist_t = 1 - peak_t + alpha_t
// Non-fired rows write zeros (replaces memset).
// ---------------------------------------------------------------------------
__global__ __launch_bounds__(256) void cif_gather(
    const float* __restrict__ hidden, const float* __restrict__ alphas2,
    const float* __restrict__ cif_peak, const int* __restrict__ fire_pos,
    const int* __restrict__ n_fires, float* __restrict__ acoustic)
{
    const int wave = blockIdx.x * 4 + (threadIdx.x >> 6);
    const int lane = threadIdx.x & 63;
    const int b = wave / T1;
    const int k = wave % T1;
    const int d0 = lane * 8;

    float4 acc0 = make_float4(0.f, 0.f, 0.f, 0.f);
    float4 acc1 = make_float4(0.f, 0.f, 0.f, 0.f);

    const int nf = n_fires[b];
    if (k < nf) {
        const int te = fire_pos[b * T1 + k];
        int ts; float wstart;
        if (k == 0) {
            ts = 0;
            wstart = alphas2[b * T1];                // alpha_0
        } else {
            ts = fire_pos[b * T1 + k - 1];
            wstart = cif_peak[b * T1 + ts] - 1.0f;   // rem at prev fire
        }
        const float ae = alphas2[b * T1 + te];
        const float wend = 1.0f - cif_peak[b * T1 + te] + ae;  // dist at te

        for (int t = ts; t <= te; ++t) {
            if (t >= TT) break;   // hidden2 row TT is zeros
            float w = (t == te) ? wend : (t == ts) ? wstart
                                       : alphas2[b * T1 + t];
            const float* hrow = hidden + (size_t)(b * TT + t) * DD + d0;
            float4 h0 = *(const float4*)hrow;
            float4 h1 = *(const float4*)(hrow + 4);
            acc0.x = fmaf(w, h0.x, acc0.x);
            acc0.y = fmaf(w, h0.y, acc0.y);
            acc0.z = fmaf(w, h0.z, acc0.z);
            acc0.w = fmaf(w, h0.w, acc0.w);
            acc1.x = fmaf(w, h1.x, acc1.x);
            acc1.y = fmaf(w, h1.y, acc1.y);
            acc1.z = fmaf(w, h1.z, acc1.z);
            acc1.w = fmaf(w, h1.w, acc1.w);
        }
    }
    float* arow = acoustic + (size_t)(b * T1 + k) * DD + d0;
    *(float4*)arow = acc0;
    *(float4*)(arow + 4) = acc1;
}

extern "C" void kernel_launch(void* const* d_in, const int* in_sizes, int n_in,
                              void* d_out, int out_size, void* d_ws, size_t ws_size,
                              hipStream_t stream) {
    const float* hidden = (const float*)d_in[0];
    const float* mask   = (const float*)d_in[1];
    const float* conv_w = (const float*)d_in[2];
    const float* conv_b = (const float*)d_in[3];
    const float* lin_w  = (const float*)d_in[4];
    const float* lin_b  = (const float*)d_in[5];

    float* out       = (float*)d_out;
    float* out_aco   = out;                                   // B*T1*D
    float* out_tok   = out + (size_t)BB * T1 * DD;            // B
    float* out_alp   = out_tok + BB;                          // B*T1
    float* out_peak  = out_alp + (size_t)BB * T1;             // B*T1

    int* fire_pos = (int*)d_ws;                               // B*T1 ints
    int* nf       = fire_pos + (size_t)BB * T1;               // B ints

    alphas_kernel<<<(BB * (TT / CH)) / 4, 256, 0, stream>>>(
        hidden, mask, conv_w, conv_b, lin_w, lin_b, out_alp);

    cif_phase_a<<<1, 256, 0, stream>>>(
        out_alp, out_tok, out_peak, fire_pos, nf);

    cif_gather<<<(BB * T1) / 4, 256, 0, stream>>>(
        hidden, out_alp, out_peak, fire_pos, nf, out_aco);
}

// Round 6
// 124.509 us; speedup vs baseline: 2.4841x; 1.2432x over previous
//
#include <hip/hip_runtime.h>
#include <math.h>

#define BB 16
#define TT 1024
#define DD 512
#define T1 (TT + 1)
#define TAIL_C 0.45f
#define CH 8   // t-rows per wave in alphas kernel

// ---------------------------------------------------------------------------
// Kernel 1: alphas2[b][t], t in [0,TT), plus tail element at t=TT.
// One wave per (b, 8 consecutive t). All 10 hidden rows loaded UP FRONT so
// the 20 dwordx4 loads are in flight together (one latency exposure/wave).
// ---------------------------------------------------------------------------
__global__ __launch_bounds__(256) void alphas_kernel(
    const float* __restrict__ hidden, const float* __restrict__ mask,
    const float* __restrict__ conv_w, const float* __restrict__ conv_b,
    const float* __restrict__ lin_w, const float* __restrict__ lin_b,
    float* __restrict__ alphas2)
{
    const int wave = blockIdx.x * 4 + (threadIdx.x >> 6);
    const int lane = threadIdx.x & 63;
    const int b = wave / (TT / CH);
    const int c = wave % (TT / CH);
    const int t0 = c * CH;
    const int d0 = lane * 8;

    // per-lane weights for channels d0..d0+7
    float cw[24], cb[8], lw[8];
    {
        const float4* p = (const float4*)(conv_w + (size_t)d0 * 3);
#pragma unroll
        for (int j = 0; j < 6; ++j) {
            float4 v = p[j];
            cw[j * 4 + 0] = v.x; cw[j * 4 + 1] = v.y;
            cw[j * 4 + 2] = v.z; cw[j * 4 + 3] = v.w;
        }
        float4 b0 = *(const float4*)(conv_b + d0);
        float4 b1 = *(const float4*)(conv_b + d0 + 4);
        cb[0]=b0.x; cb[1]=b0.y; cb[2]=b0.z; cb[3]=b0.w;
        cb[4]=b1.x; cb[5]=b1.y; cb[6]=b1.z; cb[7]=b1.w;
        float4 l0 = *(const float4*)(lin_w + d0);
        float4 l1 = *(const float4*)(lin_w + d0 + 4);
        lw[0]=l0.x; lw[1]=l0.y; lw[2]=l0.z; lw[3]=l0.w;
        lw[4]=l1.x; lw[5]=l1.y; lw[6]=l1.z; lw[7]=l1.w;
    }

    const float* base = hidden + (size_t)b * TT * DD + d0;

    // rows[r] = hidden row (t0 - 1 + r), r = 0..9; zeros outside [0, TT)
    float rows[CH + 2][8];
#pragma unroll
    for (int r = 0; r < CH + 2; ++r) {
        const int t = t0 - 1 + r;
        if (t >= 0 && t < TT) {
            float4 a  = *(const float4*)(base + (size_t)t * DD);
            float4 bq = *(const float4*)(base + (size_t)t * DD + 4);
            rows[r][0]=a.x;  rows[r][1]=a.y;  rows[r][2]=a.z;  rows[r][3]=a.w;
            rows[r][4]=bq.x; rows[r][5]=bq.y; rows[r][6]=bq.z; rows[r][7]=bq.w;
        } else {
#pragma unroll
            for (int j = 0; j < 8; ++j) rows[r][j] = 0.f;
        }
    }

    float acc[CH];
#pragma unroll
    for (int r = 0; r < CH; ++r) {
        float s = 0.f;
#pragma unroll
        for (int j = 0; j < 8; ++j) {
            float x = fmaf(cw[3*j],   rows[r][j],
                      fmaf(cw[3*j+1], rows[r+1][j],
                      fmaf(cw[3*j+2], rows[r+2][j], cb[j]))) + rows[r+1][j];
            x = fmaxf(x, 0.f);
            s = fmaf(x, lw[j], s);
        }
        acc[r] = s;
    }

    // 8 independent wave reductions (pipelined chains)
#pragma unroll
    for (int r = 0; r < CH; ++r) {
#pragma unroll
        for (int off = 32; off; off >>= 1) acc[r] += __shfl_xor(acc[r], off, 64);
    }

    if (lane < CH) {
        float v = acc[0];
#pragma unroll
        for (int r = 1; r < CH; ++r) v = (lane == r) ? acc[r] : v;
        const int t = t0 + lane;
        float logit = v + lin_b[0];
        float alpha = 1.f / (1.f + expf(-logit));
        float m = mask[b * TT + t];
        float a = fmaxf(alpha, 0.f) * m;              // SMOOTH=1, NOISE=0
        float m2 = (t == 0) ? 1.0f : mask[b * TT + t - 1];
        alphas2[(size_t)b * T1 + t] = a + (m2 - m) * TAIL_C;
    } else if (lane == CH && c == 0) {
        // tail element t = TT
        alphas2[(size_t)b * T1 + TT] = mask[b * TT + TT - 1] * TAIL_C;
    }
}

// ---------------------------------------------------------------------------
// Phase A: exact sequential integrate recurrence, one lane per batch.
// The chain wave does ONLY add + v_fract + LDS traffic (alphas staged in
// s_a, peaks written to separate s_peak -> no alias, no global stores, no
// compares on the chain). Fire compaction afterwards by all 4 waves via
// ballot+popc from LDS (coalesced fire_pos writes). Peaks written back
// cooperatively with float4 stores.
// ---------------------------------------------------------------------------
__global__ __launch_bounds__(256) void cif_phase_a(
    const float* __restrict__ alphas2, float* __restrict__ token_num,
    float* __restrict__ cif_peak, int* __restrict__ fire_pos,
    int* __restrict__ n_fires)
{
    __shared__ float s_a[BB * T1];     // 65.6 KB: staged alphas (read-only)
    __shared__ float s_peak[BB * T1];  // 65.6 KB: peaks
    const int tid = threadIdx.x;

    // stage alphas: 16400 floats = 4100 float4, both sides 16B aligned
    {
        const float4* src = (const float4*)alphas2;
        float4* dst = (float4*)s_a;
        for (int i = tid; i < (BB * T1) / 4; i += 256) dst[i] = src[i];
    }
    __syncthreads();

    // token_num = floor(sum alphas2 per batch) — identical order to r2..r4
    {
        const int b = tid >> 4, i = tid & 15;
        float part = 0.f;
        for (int t = i; t < T1; t += 16) part += s_a[b * T1 + t];
        part += __shfl_xor(part, 1, 64);
        part += __shfl_xor(part, 2, 64);
        part += __shfl_xor(part, 4, 64);
        part += __shfl_xor(part, 8, 64);
        if (i == 0) token_num[b] = floorf(part);
    }

    // serial chain: 32 chunks x 32 steps. fract(s) == reference's
    // conditional subtract-1 (exact on s in [0,2), Sterbenz).
    if (tid < BB) {
        const float* sa = s_a + tid * T1;    // stride 1025 (odd): no conflicts
        float* sp = s_peak + tid * T1;
        float integ = 0.f;
        for (int c = 0; c < 32; ++c) {
            float cur[32], pk[32];
#pragma unroll
            for (int j = 0; j < 32; ++j) cur[j] = sa[c * 32 + j];
#pragma unroll
            for (int j = 0; j < 32; ++j) {           // the chain
                float s = integ + cur[j];
                pk[j] = s;
                asm("v_fract_f32 %0, %1" : "=v"(integ) : "v"(s));
            }
#pragma unroll
            for (int j = 0; j < 32; ++j) sp[c * 32 + j] = pk[j];
        }
        float s = integ + sa[TT];                    // tail t = 1024
        sp[TT] = s;
    }
    __syncthreads();

    // cooperative writeback of peaks
    {
        const float4* src = (const float4*)s_peak;
        float4* dst = (float4*)cif_peak;
        for (int i = tid; i < (BB * T1) / 4; i += 256) dst[i] = src[i];
    }

    // fire compaction: wave w handles batches 4w..4w+3; ballot + rank.
    {
        const int wv = tid >> 6, lane = tid & 63;
        for (int bi = 0; bi < 4; ++bi) {
            const int b = wv * 4 + bi;
            const float* sp = s_peak + b * T1;
            int k0 = 0;
            for (int base = 0; base < T1; base += 64) {
                const int t = base + lane;
                const float p = (t < T1) ? sp[t] : 0.f;
                const bool fire = (p >= 1.0f);
                unsigned long long mballot = __ballot(fire);
                if (fire) {
                    int rank = __popcll(mballot & ((1ull << lane) - 1));
                    fire_pos[b * T1 + k0 + rank] = t;
                }
                k0 += __popcll(mballot);
            }
            if (lane == 0) n_fires[b] = k0;
        }
    }
}

// ---------------------------------------------------------------------------
// Phase B: one wave per acoustic output row. Fired rows = segment-weighted
// sum of hidden rows; boundary weights reconstructed from peak/alphas:
//   rem_t  = peak_t - 1
//   dist_t = 1 - peak_t + alpha_t
// Non-fired rows write zeros (replaces memset).
// ---------------------------------------------------------------------------
__global__ __launch_bounds__(256) void cif_gather(
    const float* __restrict__ hidden, const float* __restrict__ alphas2,
    const float* __restrict__ cif_peak, const int* __restrict__ fire_pos,
    const int* __restrict__ n_fires, float* __restrict__ acoustic)
{
    const int wave = blockIdx.x * 4 + (threadIdx.x >> 6);
    const int lane = threadIdx.x & 63;
    const int b = wave / T1;
    const int k = wave % T1;
    const int d0 = lane * 8;

    float4 acc0 = make_float4(0.f, 0.f, 0.f, 0.f);
    float4 acc1 = make_float4(0.f, 0.f, 0.f, 0.f);

    const int nf = n_fires[b];
    if (k < nf) {
        const int te = fire_pos[b * T1 + k];
        int ts; float wstart;
        if (k == 0) {
            ts = 0;
            wstart = alphas2[b * T1];                // alpha_0
        } else {
            ts = fire_pos[b * T1 + k - 1];
            wstart = cif_peak[b * T1 + ts] - 1.0f;   // rem at prev fire
        }
        const float ae = alphas2[b * T1 + te];
        const float wend = 1.0f - cif_peak[b * T1 + te] + ae;  // dist at te

        for (int t = ts; t <= te; ++t) {
            if (t >= TT) break;   // hidden2 row TT is zeros
            float w = (t == te) ? wend : (t == ts) ? wstart
                                       : alphas2[b * T1 + t];
            const float* hrow = hidden + (size_t)(b * TT + t) * DD + d0;
            float4 h0 = *(const float4*)hrow;
            float4 h1 = *(const float4*)(hrow + 4);
            acc0.x = fmaf(w, h0.x, acc0.x);
            acc0.y = fmaf(w, h0.y, acc0.y);
            acc0.z = fmaf(w, h0.z, acc0.z);
            acc0.w = fmaf(w, h0.w, acc0.w);
            acc1.x = fmaf(w, h1.x, acc1.x);
            acc1.y = fmaf(w, h1.y, acc1.y);
            acc1.z = fmaf(w, h1.z, acc1.z);
            acc1.w = fmaf(w, h1.w, acc1.w);
        }
    }
    float* arow = acoustic + (size_t)(b * T1 + k) * DD + d0;
    *(float4*)arow = acc0;
    *(float4*)(arow + 4) = acc1;
}

extern "C" void kernel_launch(void* const* d_in, const int* in_sizes, int n_in,
                              void* d_out, int out_size, void* d_ws, size_t ws_size,
                              hipStream_t stream) {
    const float* hidden = (const float*)d_in[0];
    const float* mask   = (const float*)d_in[1];
    const float* conv_w = (const float*)d_in[2];
    const float* conv_b = (const float*)d_in[3];
    const float* lin_w  = (const float*)d_in[4];
    const float* lin_b  = (const float*)d_in[5];

    float* out       = (float*)d_out;
    float* out_aco   = out;                                   // B*T1*D
    float* out_tok   = out + (size_t)BB * T1 * DD;            // B
    float* out_alp   = out_tok + BB;                          // B*T1
    float* out_peak  = out_alp + (size_t)BB * T1;             // B*T1

    int* fire_pos = (int*)d_ws;                               // B*T1 ints
    int* nf       = fire_pos + (size_t)BB * T1;               // B ints

    alphas_kernel<<<(BB * (TT / CH)) / 4, 256, 0, stream>>>(
        hidden, mask, conv_w, conv_b, lin_w, lin_b, out_alp);

    cif_phase_a<<<1, 256, 0, stream>>>(
        out_alp, out_tok, out_peak, fire_pos, nf);

    cif_gather<<<(BB * T1) / 4, 256, 0, stream>>>(
        hidden, out_alp, out_peak, fire_pos, nf, out_aco);
}

// Round 7
// 124.246 us; speedup vs baseline: 2.4893x; 1.0021x over previous
//
#include <hip/hip_runtime.h>
#include <math.h>

#define BB 16
#define TT 1024
#define DD 512
#define T1 (TT + 1)
#define PS 1028   // padded per-batch LDS stride (floats): 1028*4 % 16 == 0
#define TAIL_C 0.45f
#define CH 8      // t-rows per wave in alphas kernel

// ---------------------------------------------------------------------------
// Kernel 1: alphas2[b][t], t in [0,TT), plus tail element at t=TT.
// One wave per (b, 8 consecutive t). All 10 hidden rows loaded UP FRONT so
// the 20 dwordx4 loads are in flight together (one latency exposure/wave).
// (unchanged from r6)
// ---------------------------------------------------------------------------
__global__ __launch_bounds__(256) void alphas_kernel(
    const float* __restrict__ hidden, const float* __restrict__ mask,
    const float* __restrict__ conv_w, const float* __restrict__ conv_b,
    const float* __restrict__ lin_w, const float* __restrict__ lin_b,
    float* __restrict__ alphas2)
{
    const int wave = blockIdx.x * 4 + (threadIdx.x >> 6);
    const int lane = threadIdx.x & 63;
    const int b = wave / (TT / CH);
    const int c = wave % (TT / CH);
    const int t0 = c * CH;
    const int d0 = lane * 8;

    float cw[24], cb[8], lw[8];
    {
        const float4* p = (const float4*)(conv_w + (size_t)d0 * 3);
#pragma unroll
        for (int j = 0; j < 6; ++j) {
            float4 v = p[j];
            cw[j * 4 + 0] = v.x; cw[j * 4 + 1] = v.y;
            cw[j * 4 + 2] = v.z; cw[j * 4 + 3] = v.w;
        }
        float4 b0 = *(const float4*)(conv_b + d0);
        float4 b1 = *(const float4*)(conv_b + d0 + 4);
        cb[0]=b0.x; cb[1]=b0.y; cb[2]=b0.z; cb[3]=b0.w;
        cb[4]=b1.x; cb[5]=b1.y; cb[6]=b1.z; cb[7]=b1.w;
        float4 l0 = *(const float4*)(lin_w + d0);
        float4 l1 = *(const float4*)(lin_w + d0 + 4);
        lw[0]=l0.x; lw[1]=l0.y; lw[2]=l0.z; lw[3]=l0.w;
        lw[4]=l1.x; lw[5]=l1.y; lw[6]=l1.z; lw[7]=l1.w;
    }

    const float* base = hidden + (size_t)b * TT * DD + d0;

    float rows[CH + 2][8];
#pragma unroll
    for (int r = 0; r < CH + 2; ++r) {
        const int t = t0 - 1 + r;
        if (t >= 0 && t < TT) {
            float4 a  = *(const float4*)(base + (size_t)t * DD);
            float4 bq = *(const float4*)(base + (size_t)t * DD + 4);
            rows[r][0]=a.x;  rows[r][1]=a.y;  rows[r][2]=a.z;  rows[r][3]=a.w;
            rows[r][4]=bq.x; rows[r][5]=bq.y; rows[r][6]=bq.z; rows[r][7]=bq.w;
        } else {
#pragma unroll
            for (int j = 0; j < 8; ++j) rows[r][j] = 0.f;
        }
    }

    float acc[CH];
#pragma unroll
    for (int r = 0; r < CH; ++r) {
        float s = 0.f;
#pragma unroll
        for (int j = 0; j < 8; ++j) {
            float x = fmaf(cw[3*j],   rows[r][j],
                      fmaf(cw[3*j+1], rows[r+1][j],
                      fmaf(cw[3*j+2], rows[r+2][j], cb[j]))) + rows[r+1][j];
            x = fmaxf(x, 0.f);
            s = fmaf(x, lw[j], s);
        }
        acc[r] = s;
    }

#pragma unroll
    for (int r = 0; r < CH; ++r) {
#pragma unroll
        for (int off = 32; off; off >>= 1) acc[r] += __shfl_xor(acc[r], off, 64);
    }

    if (lane < CH) {
        float v = acc[0];
#pragma unroll
        for (int r = 1; r < CH; ++r) v = (lane == r) ? acc[r] : v;
        const int t = t0 + lane;
        float logit = v + lin_b[0];
        float alpha = 1.f / (1.f + expf(-logit));
        float m = mask[b * TT + t];
        float a = fmaxf(alpha, 0.f) * m;              // SMOOTH=1, NOISE=0
        float m2 = (t == 0) ? 1.0f : mask[b * TT + t - 1];
        alphas2[(size_t)b * T1 + t] = a + (m2 - m) * TAIL_C;
    } else if (lane == CH && c == 0) {
        alphas2[(size_t)b * T1 + TT] = mask[b * TT + TT - 1] * TAIL_C;
    }
}

// 32-step chain over one chunk held in 8 float4 registers.
// fract(s) == reference's conditional subtract-1 (exact on s in [0,2)).
__device__ __forceinline__ void chain32(const float4* buf, float& integ,
                                        float4* out) {
#pragma unroll
    for (int j = 0; j < 8; ++j) {
        float4 v = buf[j];
        float4 o;
        float s;
        s = integ + v.x; o.x = s; asm("v_fract_f32 %0, %1" : "=v"(integ) : "v"(s));
        s = integ + v.y; o.y = s; asm("v_fract_f32 %0, %1" : "=v"(integ) : "v"(s));
        s = integ + v.z; o.z = s; asm("v_fract_f32 %0, %1" : "=v"(integ) : "v"(s));
        s = integ + v.w; o.w = s; asm("v_fract_f32 %0, %1" : "=v"(integ) : "v"(s));
        out[j] = o;
    }
}

// ---------------------------------------------------------------------------
// Phase A: exact sequential integrate recurrence, one lane per batch.
// LDS rows padded to PS=1028 floats -> 16B-aligned -> chain I/O runs as
// ds_read_b128/ds_write_b128, explicitly double-buffered at chunk level so
// the next chunk's 8 wide reads are in flight UNDER the current 32-step
// chain (fixes r6's per-step lazy ds_read + lgkmcnt(0) stall).
// ---------------------------------------------------------------------------
__global__ __launch_bounds__(256) void cif_phase_a(
    const float* __restrict__ alphas2, float* __restrict__ token_num,
    float* __restrict__ cif_peak, int* __restrict__ fire_pos,
    int* __restrict__ n_fires)
{
    __shared__ float s_a[BB * PS];     // 65.8 KB: staged alphas (padded rows)
    __shared__ float s_peak[BB * PS];  // 65.8 KB: peaks (padded rows)
    const int tid = threadIdx.x;

    // stage alphas: float4 global loads, scatter into padded LDS rows
    {
        const float4* src = (const float4*)alphas2;
        for (int i = tid; i < (BB * T1) / 4; i += 256) {
            float4 v = src[i];
            const int e = i * 4;
            int b = e / T1;                 // magic-mul div by constant
            int t = e - b * T1;
            float el[4] = {v.x, v.y, v.z, v.w};
#pragma unroll
            for (int j = 0; j < 4; ++j) {
                int bb = b, tt = t + j;
                if (tt >= T1) { bb += 1; tt -= T1; }
                s_a[bb * PS + tt] = el[j];
            }
        }
    }
    __syncthreads();

    // token_num = floor(sum alphas2 per batch) — identical order to r2..r6
    {
        const int b = tid >> 4, i = tid & 15;
        float part = 0.f;
        for (int t = i; t < T1; t += 16) part += s_a[b * PS + t];
        part += __shfl_xor(part, 1, 64);
        part += __shfl_xor(part, 2, 64);
        part += __shfl_xor(part, 4, 64);
        part += __shfl_xor(part, 8, 64);
        if (i == 0) token_num[b] = floorf(part);
    }

    // serial chain: 32 chunks x 32 steps, chunk-level register double buffer
    if (tid < BB) {
        const float4* sa4 = (const float4*)(s_a + tid * PS);
        float4* sp4 = (float4*)(s_peak + tid * PS);
        float4 A[8], Bv[8], OA[8], OB[8];
#pragma unroll
        for (int j = 0; j < 8; ++j) A[j] = sa4[j];          // chunk 0
        float integ = 0.f;
        for (int c = 0; c < 32; c += 2) {
#pragma unroll
            for (int j = 0; j < 8; ++j) Bv[j] = sa4[(c + 1) * 8 + j];
            chain32(A, integ, OA);
#pragma unroll
            for (int j = 0; j < 8; ++j) sp4[c * 8 + j] = OA[j];
            if (c + 2 < 32) {
#pragma unroll
                for (int j = 0; j < 8; ++j) A[j] = sa4[(c + 2) * 8 + j];
            }
            chain32(Bv, integ, OB);
#pragma unroll
            for (int j = 0; j < 8; ++j) sp4[(c + 1) * 8 + j] = OB[j];
        }
        // tail t = 1024
        float s = integ + s_a[tid * PS + TT];
        s_peak[tid * PS + TT] = s;
    }
    __syncthreads();

    // cooperative writeback of peaks (padded LDS -> flat global, float4)
    {
        float4* dst = (float4*)cif_peak;
        for (int i = tid; i < (BB * T1) / 4; i += 256) {
            const int e = i * 4;
            int b = e / T1;
            int t = e - b * T1;
            float4 v;
            float* pv = &v.x;
#pragma unroll
            for (int j = 0; j < 4; ++j) {
                int bb = b, tt = t + j;
                if (tt >= T1) { bb += 1; tt -= T1; }
                pv[j] = s_peak[bb * PS + tt];
            }
            dst[i] = v;
        }
    }

    // fire compaction: wave w handles batches 4w..4w+3; ballot + rank.
    {
        const int wv = tid >> 6, lane = tid & 63;
        for (int bi = 0; bi < 4; ++bi) {
            const int b = wv * 4 + bi;
            const float* sp = s_peak + b * PS;
            int k0 = 0;
            for (int base = 0; base < T1; base += 64) {
                const int t = base + lane;
                const float p = (t < T1) ? sp[t] : 0.f;
                const bool fire = (p >= 1.0f);
                unsigned long long mballot = __ballot(fire);
                if (fire) {
                    int rank = __popcll(mballot & ((1ull << lane) - 1));
                    fire_pos[b * T1 + k0 + rank] = t;
                }
                k0 += __popcll(mballot);
            }
            if (lane == 0) n_fires[b] = k0;
        }
    }
}

// ---------------------------------------------------------------------------
// Phase B: one wave per acoustic output row. Fired rows = segment-weighted
// sum of hidden rows; boundary weights reconstructed from peak/alphas:
//   rem_t  = peak_t - 1
//   dist_t = 1 - peak_t + alpha_t
// Non-fired rows write zeros (replaces memset). (unchanged from r6)
// ---------------------------------------------------------------------------
__global__ __launch_bounds__(256) void cif_gather(
    const float* __restrict__ hidden, const float* __restrict__ alphas2,
    const float* __restrict__ cif_peak, const int* __restrict__ fire_pos,
    const int* __restrict__ n_fires, float* __restrict__ acoustic)
{
    const int wave = blockIdx.x * 4 + (threadIdx.x >> 6);
    const int lane = threadIdx.x & 63;
    const int b = wave / T1;
    const int k = wave % T1;
    const int d0 = lane * 8;

    float4 acc0 = make_float4(0.f, 0.f, 0.f, 0.f);
    float4 acc1 = make_float4(0.f, 0.f, 0.f, 0.f);

    const int nf = n_fires[b];
    if (k < nf) {
        const int te = fire_pos[b * T1 + k];
        int ts; float wstart;
        if (k == 0) {
            ts = 0;
            wstart = alphas2[b * T1];                // alpha_0
        } else {
            ts = fire_pos[b * T1 + k - 1];
            wstart = cif_peak[b * T1 + ts] - 1.0f;   // rem at prev fire
        }
        const float ae = alphas2[b * T1 + te];
        const float wend = 1.0f - cif_peak[b * T1 + te] + ae;  // dist at te

        for (int t = ts; t <= te; ++t) {
            if (t >= TT) break;   // hidden2 row TT is zeros
            float w = (t == te) ? wend : (t == ts) ? wstart
                                       : alphas2[b * T1 + t];
            const float* hrow = hidden + (size_t)(b * TT + t) * DD + d0;
            float4 h0 = *(const float4*)hrow;
            float4 h1 = *(const float4*)(hrow + 4);
            acc0.x = fmaf(w, h0.x, acc0.x);
            acc0.y = fmaf(w, h0.y, acc0.y);
            acc0.z = fmaf(w, h0.z, acc0.z);
            acc0.w = fmaf(w, h0.w, acc0.w);
            acc1.x = fmaf(w, h1.x, acc1.x);
            acc1.y = fmaf(w, h1.y, acc1.y);
            acc1.z = fmaf(w, h1.z, acc1.z);
            acc1.w = fmaf(w, h1.w, acc1.w);
        }
    }
    float* arow = acoustic + (size_t)(b * T1 + k) * DD + d0;
    *(float4*)arow = acc0;
    *(float4*)(arow + 4) = acc1;
}

extern "C" void kernel_launch(void* const* d_in, const int* in_sizes, int n_in,
                              void* d_out, int out_size, void* d_ws, size_t ws_size,
                              hipStream_t stream) {
    const float* hidden = (const float*)d_in[0];
    const float* mask   = (const float*)d_in[1];
    const float* conv_w = (const float*)d_in[2];
    const float* conv_b = (const float*)d_in[3];
    const float* lin_w  = (const float*)d_in[4];
    const float* lin_b  = (const float*)d_in[5];

    float* out       = (float*)d_out;
    float* out_aco   = out;                                   // B*T1*D
    float* out_tok   = out + (size_t)BB * T1 * DD;            // B
    float* out_alp   = out_tok + BB;                          // B*T1
    float* out_peak  = out_alp + (size_t)BB * T1;             // B*T1

    int* fire_pos = (int*)d_ws;                               // B*T1 ints
    int* nf       = fire_pos + (size_t)BB * T1;               // B ints

    alphas_kernel<<<(BB * (TT / CH)) / 4, 256, 0, stream>>>(
        hidden, mask, conv_w, conv_b, lin_w, lin_b, out_alp);

    cif_phase_a<<<1, 256, 0, stream>>>(
        out_alp, out_tok, out_peak, fire_pos, nf);

    cif_gather<<<(BB * T1) / 4, 256, 0, stream>>>(
        hidden, out_alp, out_peak, fire_pos, nf, out_aco);
}